// Round 1
// baseline (13350.638 us; speedup 1.0000x reference)
//
#include <hip/hip_runtime.h>
#include <hip/hip_bf16.h>
#include <stdint.h>

#define T_STEPS 512
#define NBATCH 64
#define HID 1024
#define NGATE 4096
#define NLAYERS 2
#define TCHUNK 128

typedef __attribute__((ext_vector_type(8))) short short8;
typedef __attribute__((ext_vector_type(4))) float f32x4;
typedef __attribute__((ext_vector_type(16))) float f32x16;

__device__ __forceinline__ ushort f2bf(float f) {
  union { float f; uint32_t i; } u; u.f = f;
  uint32_t r = (u.i + 0x7fffu + ((u.i >> 16) & 1u)) >> 16;  // RNE
  return (ushort)r;
}
__device__ __forceinline__ float bf2f(ushort b) {
  union { uint32_t i; float f; } u; u.i = ((uint32_t)b) << 16;
  return u.f;
}

__device__ __forceinline__ void gll16(const void* g, void* l) {
  __builtin_amdgcn_global_load_lds(
      (const __attribute__((address_space(1))) unsigned int*)g,
      (__attribute__((address_space(3))) unsigned int*)l, 16, 0, 0);
}

// ---------------- elementwise helpers ----------------
__global__ void k_f32_to_bf16(const float* __restrict__ in, ushort* __restrict__ out, int n) {
  int i = (blockIdx.x * blockDim.x + threadIdx.x) * 4;
  if (i >= n) return;
  const float4 v = *reinterpret_cast<const float4*>(in + i);
  ushort4 o; o.x = f2bf(v.x); o.y = f2bf(v.y); o.z = f2bf(v.z); o.w = f2bf(v.w);
  *reinterpret_cast<ushort4*>(out + i) = o;
}

__global__ void k_copy_f32(const float* __restrict__ in, float* __restrict__ out, int n) {
  int i = (blockIdx.x * blockDim.x + threadIdx.x) * 4;
  if (i >= n) return;
  *reinterpret_cast<float4*>(out + i) = *reinterpret_cast<const float4*>(in + i);
}

// ---------------- igates GEMM: C(M,4096) = A(M,1024) * W(4096,1024)^T + b1 + b2 ----------------
// m97 structure: 128x128 tile, BK=64, 4 waves (2x2), 16x16x32 bf16 MFMA, swizzled LDS,
// global_load_lds width 16 with pre-swizzled global source.
__global__ __launch_bounds__(256) void k_gemm_ig(
    const ushort* __restrict__ A, const ushort* __restrict__ W,
    const float* __restrict__ bia, const float* __restrict__ bib,
    ushort* __restrict__ C)
{
  __shared__ __align__(16) ushort At[128 * 64];
  __shared__ __align__(16) ushort Bt[128 * 64];
  const int tid = threadIdx.x;
  const int wave = tid >> 6, lane = tid & 63;
  const int m0 = blockIdx.x * 128;
  const int n0 = blockIdx.y * 128;
  const int wr = wave >> 1, wc = wave & 1;

  // staging: round i writes LDS bytes [i*4096 + wave*1024 + lane*16); row r = i*32 + r_st
  const int r_st = wave * 8 + (lane >> 3);
  const int bsw = ((lane & 7) * 16) ^ ((r_st & 7) << 4);  // pre-swizzled byte-in-row
  const ushort* aSrc = A + (size_t)(m0 + r_st) * 1024 + (bsw >> 1);
  const ushort* bSrc = W + (size_t)(n0 + r_st) * 1024 + (bsw >> 1);
  ushort* aDst = At + wave * 512;
  ushort* bDst = Bt + wave * 512;

  f32x4 acc[4][4];
#pragma unroll
  for (int a = 0; a < 4; ++a)
#pragma unroll
    for (int b = 0; b < 4; ++b) acc[a][b] = (f32x4){0.f, 0.f, 0.f, 0.f};

  for (int ks = 0; ks < 16; ++ks) {
#pragma unroll
    for (int i = 0; i < 4; ++i) {
      gll16(aSrc + (size_t)i * 32 * 1024 + ks * 64, aDst + i * 2048);
      gll16(bSrc + (size_t)i * 32 * 1024 + ks * 64, bDst + i * 2048);
    }
    __syncthreads();  // drains vmcnt(0): LDS tiles ready
#pragma unroll
    for (int kc = 0; kc < 2; ++kc) {
      const int kb = kc * 64 + (lane >> 4) * 16;  // byte-in-row for this frag
      short8 af[4], bfr[4];
#pragma unroll
      for (int mt = 0; mt < 4; ++mt) {
        const int r = wr * 64 + mt * 16 + (lane & 15);
        af[mt] = *(const short8*)((const char*)At + r * 128 + (kb ^ ((r & 7) << 4)));
      }
#pragma unroll
      for (int nt = 0; nt < 4; ++nt) {
        const int r = wc * 64 + nt * 16 + (lane & 15);
        bfr[nt] = *(const short8*)((const char*)Bt + r * 128 + (kb ^ ((r & 7) << 4)));
      }
#pragma unroll
      for (int mt = 0; mt < 4; ++mt)
#pragma unroll
        for (int nt = 0; nt < 4; ++nt)
          acc[mt][nt] = __builtin_amdgcn_mfma_f32_16x16x32_bf16(af[mt], bfr[nt], acc[mt][nt], 0, 0, 0);
    }
    __syncthreads();  // before next stage overwrites LDS
  }

#pragma unroll
  for (int nt = 0; nt < 4; ++nt) {
    const int col = n0 + wc * 64 + nt * 16 + (lane & 15);
    const float bias = bia[col] + bib[col];
#pragma unroll
    for (int mt = 0; mt < 4; ++mt) {
      const int row = m0 + wr * 64 + mt * 16 + (lane >> 4) * 4;
      const f32x4 v = acc[mt][nt];
#pragma unroll
      for (int r = 0; r < 4; ++r)
        C[(size_t)(row + r) * 4096 + col] = f2bf(v[r] + bias);
    }
  }
}

// ---------------- one LSTM timestep (fused gates+nonlinearity) ----------------
// grid 128 blocks x 128 threads. Block owns 8 h-columns (j0..j0+7) x 4 gate families
// = 32 rows of W_hh, staged in swizzled LDS. gates(64x32) = h(64x1024) @ Wslice^T
// via mfma_f32_32x32x16_bf16 (wave = 32 batches x 32 cols), A-frags direct from L2.
__global__ __launch_bounds__(128) void k_lstm_step(
    const ushort* __restrict__ hprev,   // (64,1024) bf16
    const ushort* __restrict__ Whh,     // (4096,1024) bf16, layer base
    const ushort* __restrict__ igt,     // (64,4096) bf16, this timestep (biases folded)
    float* __restrict__ cbuf,           // (64,1024) f32 in-place
    ushort* __restrict__ hout,          // (64,1024) bf16
    float* __restrict__ outp,           // (64,1024) f32 or null
    float* __restrict__ hfin,           // null except t==T-1
    float* __restrict__ cfin)
{
  __shared__ __align__(16) ushort Wl[32 * 1024];  // 64 KB, rows 2048 B, XOR-swizzled
  __shared__ float glds[64 * 33];
  const int tid = threadIdx.x;
  const int wave = tid >> 6, lane = tid & 63;
  const int j0 = blockIdx.x * 8;

  {  // stage W slice: LDS row i <- W row (i>>3)*1024 + j0 + (i&7); pre-swizzled source
    const int bp = wave * 1024 + lane * 16;
#pragma unroll
    for (int i = 0; i < 32; ++i) {
      const ushort* src = Whh + (size_t)((i >> 3) * 1024 + j0 + (i & 7)) * 1024
                          + ((bp ^ ((i & 7) << 4)) >> 1);
      gll16(src, Wl + i * 1024 + wave * 512);
    }
  }

  const int mrow = wave * 32 + (lane & 31);
  const ushort* aptr = hprev + (size_t)mrow * 1024 + (lane >> 5) * 8;
  const int brow = lane & 31;
  const char* bbase = (const char*)Wl + brow * 2048;
  const int bswz = (brow & 7) << 4;
  const int khalf = (lane >> 5) * 16;

  f32x16 acc0, acc1;
#pragma unroll
  for (int r = 0; r < 16; ++r) { acc0[r] = 0.f; acc1[r] = 0.f; }

  __syncthreads();  // W staged (vmcnt drained)

#pragma unroll 4
  for (int kc = 0; kc < 64; kc += 2) {  // two accumulation chains for MFMA ILP
    short8 a0 = *(const short8*)(aptr + kc * 16);
    short8 a1 = *(const short8*)(aptr + kc * 16 + 16);
    short8 b0 = *(const short8*)(bbase + ((kc * 32 + khalf) ^ bswz));
    short8 b1 = *(const short8*)(bbase + (((kc + 1) * 32 + khalf) ^ bswz));
    acc0 = __builtin_amdgcn_mfma_f32_32x32x16_bf16(a0, b0, acc0, 0, 0, 0);
    acc1 = __builtin_amdgcn_mfma_f32_32x32x16_bf16(a1, b1, acc1, 0, 0, 0);
  }

  // C layout (32x32): col = lane&31, row = (reg&3) + 8*(reg>>2) + 4*(lane>>5)
#pragma unroll
  for (int r = 0; r < 16; ++r) {
    const int row = wave * 32 + (r & 3) + 8 * (r >> 2) + 4 * (lane >> 5);
    glds[row * 33 + brow] = acc0[r] + acc1[r];
  }
  __syncthreads();

#pragma unroll
  for (int i = 0; i < 4; ++i) {
    const int idx = tid + 128 * i;          // 512 outputs: b = idx>>3, jl = idx&7
    const int b = idx >> 3, jl = idx & 7;
    const int j = j0 + jl;
    const float gi = glds[b * 33 + jl]      + bf2f(igt[b * 4096 + j]);
    const float gf = glds[b * 33 + 8 + jl]  + bf2f(igt[b * 4096 + 1024 + j]);
    const float gg = glds[b * 33 + 16 + jl] + bf2f(igt[b * 4096 + 2048 + j]);
    const float go = glds[b * 33 + 24 + jl] + bf2f(igt[b * 4096 + 3072 + j]);
    float c = cbuf[b * 1024 + j];
    const float si = 1.f / (1.f + __expf(-gi));
    const float sf = 1.f / (1.f + __expf(-gf));
    const float so = 1.f / (1.f + __expf(-go));
    const float tg = tanhf(gg);
    c = sf * c + si * tg;
    const float h = so * tanhf(c);
    cbuf[b * 1024 + j] = c;
    hout[b * 1024 + j] = f2bf(h);
    if (outp) outp[b * 1024 + j] = h;
    if (hfin) { hfin[b * 1024 + j] = h; cfin[b * 1024 + j] = c; }
  }
}

// ---------------- host ----------------
extern "C" void kernel_launch(void* const* d_in, const int* in_sizes, int n_in,
                              void* d_out, int out_size, void* d_ws, size_t ws_size,
                              hipStream_t stream) {
  const float* x    = (const float*)d_in[0];
  const float* h0   = (const float*)d_in[1];
  const float* c0   = (const float*)d_in[2];
  const float* w_ih = (const float*)d_in[3];
  const float* w_hh = (const float*)d_in[4];
  const float* b_ih = (const float*)d_in[5];
  const float* b_hh = (const float*)d_in[6];
  float* out = (float*)d_out;

  const int TBH = T_STEPS * NBATCH * HID;   // 33,554,432
  const int BH  = NBATCH * HID;             // 65,536
  const size_t WEL = (size_t)NLAYERS * NGATE * HID;

  ushort* xb    = (ushort*)d_ws;
  ushort* seq0  = xb + (size_t)TBH;
  ushort* wihb  = seq0 + (size_t)TBH;
  ushort* whhb  = wihb + WEL;
  ushort* ig    = whhb + WEL;
  ushort* h0b   = ig + (size_t)TCHUNK * NBATCH * NGATE;
  ushort* hping = h0b + (size_t)NLAYERS * BH;
  float*  cbuf  = (float*)(hping + 2 * (size_t)BH);

  const size_t need = ((size_t)2 * TBH + 2 * WEL + (size_t)TCHUNK * NBATCH * NGATE
                       + (size_t)NLAYERS * BH + 2 * (size_t)BH) * 2 + (size_t)BH * 4;
  if (ws_size < need) return;  // loud failure: d_out stays poisoned

  { int n = TBH;            k_f32_to_bf16<<<(n/4 + 255)/256, 256, 0, stream>>>(x, xb, n); }
  { int n = (int)WEL;       k_f32_to_bf16<<<(n/4 + 255)/256, 256, 0, stream>>>(w_ih, wihb, n); }
  { int n = (int)WEL;       k_f32_to_bf16<<<(n/4 + 255)/256, 256, 0, stream>>>(w_hh, whhb, n); }
  { int n = NLAYERS * BH;   k_f32_to_bf16<<<(n/4 + 255)/256, 256, 0, stream>>>(h0, h0b, n); }

  for (int l = 0; l < NLAYERS; ++l) {
    k_copy_f32<<<(BH/4 + 255)/256, 256, 0, stream>>>(c0 + (size_t)l * BH, cbuf, BH);
    const ushort* Aseq = (l == 0) ? xb : seq0;
    const ushort* Wih  = wihb + (size_t)l * NGATE * HID;
    const ushort* Whh  = whhb + (size_t)l * NGATE * HID;
    const float*  bi   = b_ih + (size_t)l * NGATE;
    const float*  bh   = b_hh + (size_t)l * NGATE;

    for (int tc = 0; tc < T_STEPS / TCHUNK; ++tc) {
      dim3 g(TCHUNK * NBATCH / 128, NGATE / 128);
      k_gemm_ig<<<g, 256, 0, stream>>>(Aseq + (size_t)tc * TCHUNK * NBATCH * HID,
                                       Wih, bi, bh, ig);
      for (int tl = 0; tl < TCHUNK; ++tl) {
        const int t = tc * TCHUNK + tl;
        const ushort* hp;
        if (t == 0)      hp = h0b + (size_t)l * BH;
        else if (l == 0) hp = seq0 + (size_t)(t - 1) * BH;
        else             hp = hping + (size_t)((t - 1) & 1) * BH;
        ushort* ho = (l == 0) ? (seq0 + (size_t)t * BH) : (hping + (size_t)(t & 1) * BH);
        float* op = (l == NLAYERS - 1) ? (out + (size_t)t * BH) : nullptr;
        float* hf = nullptr; float* cf = nullptr;
        if (t == T_STEPS - 1) {
          hf = out + (size_t)TBH + (size_t)l * BH;
          cf = out + (size_t)TBH + (size_t)NLAYERS * BH + (size_t)l * BH;
        }
        k_lstm_step<<<128, 128, 0, stream>>>(hp, Whh, ig + (size_t)tl * NBATCH * NGATE,
                                             cbuf, ho, op, hf, cf);
      }
    }
  }
}